// Round 21
// baseline (683.210 us; speedup 1.0000x reference)
//
#include <hip/hip_runtime.h>
#include <hip/hip_fp16.h>
#include <cstdint>

#define NT 256
#define PA 128                 // prep atoms per block (4 waves x 2 M-tiles)
#define N_ATOMS_C 600000
#define BATCH_C 24000
#define BT_STRIDE 104          // Bt k-stride (halves)
#define SO_STRIDE 88           // sout row stride (halves, 16B-aligned rows)

constexpr int K_COUNTS[11] = {10000,130000,170000,160000,100000,15000,5000,2500,2500,2500,2500};
constexpr int K_STARTS[11] = {0,10000,140000,310000,470000,570000,585000,590000,592500,595000,597500};
// heavy-degree-first dispatch order
constexpr int DORD[11] = {10,9,8,7,6,5,4,3,2,1,0};

struct AdjPtrs { const int* p[10]; };

typedef _Float16 f16x8 __attribute__((ext_vector_type(8)));
typedef float f32x4 __attribute__((ext_vector_type(4)));

__device__ __forceinline__ float selu_f(float x) {
    const float scale = 1.0507009873554805f;
    const float alpha = 1.6732632423543772f;
    return scale * (x > 0.f ? x : alpha * expm1f(x));
}

__device__ __forceinline__ float2 up2(unsigned u) {
    const __half2 h = __builtin_bit_cast(__half2, u);
    return __half22float2(h);
}
__device__ __forceinline__ unsigned pack2(float a, float b) {
    const __half2 h = __float22half2_rn(make_float2(a, b));
    return __builtin_bit_cast(unsigned, h);
}

template<int NU4>
__device__ __forceinline__ void load_row4(const uint4* __restrict__ p, float* r) {
#pragma unroll
    for (int v = 0; v < NU4; ++v) {
        const uint4 t = p[v];
        const float2 a = up2(t.x), b = up2(t.y), c = up2(t.z), d = up2(t.w);
        r[8*v]   = a.x; r[8*v+1] = a.y; r[8*v+2] = b.x; r[8*v+3] = b.y;
        r[8*v+4] = c.x; r[8*v+5] = c.y; r[8*v+6] = d.x; r[8*v+7] = d.y;
    }
}
template<int NU4>
__device__ __forceinline__ void acc_u4(const uint4* t, float* r) {
#pragma unroll
    for (int v = 0; v < NU4; ++v) {
        const float2 a = up2(t[v].x), b = up2(t[v].y), c = up2(t[v].z), d = up2(t[v].w);
        r[8*v]   += a.x; r[8*v+1] += a.y; r[8*v+2] += b.x; r[8*v+3] += b.y;
        r[8*v+4] += c.x; r[8*v+5] += c.y; r[8*v+6] += d.x; r[8*v+7] += d.y;
    }
}
template<int NF, int FO>
__device__ __forceinline__ void fma_strip(const float* r, const float* __restrict__ w,
                                          float* acc) {
#pragma unroll
    for (int f = 0; f < NF; ++f)
#pragma unroll
        for (int o = 0; o < FO; ++o)
            acc[o] = fmaf(r[f], w[f * FO + o], acc[o]);
}

// block -> (degree, segment start, count, tile index within segment)
template<int TB>
__device__ __forceinline__ void blk2degT(int blk, int& deg, int& s, int& cnt, int& tile) {
    deg = 0; s = 0; cnt = 0; tile = 0;
#pragma unroll
    for (int di = 0; di < 11; ++di) {
        const int d = DORD[di];
        const int nb = (K_COUNTS[d] + TB - 1) / TB;
        if (blk < nb) { deg = d; s = K_STARTS[d]; cnt = K_COUNTS[d]; tile = blk; return; }
        blk -= nb;
    }
}

// ---------------------------------------------------------------------------
// bprep (+ fused cnt zeroing): build fp16 B^T tiles ONCE.
// ---------------------------------------------------------------------------
__global__ __launch_bounds__(256) void bprep_kernel(const float* __restrict__ W,
                                                    unsigned short* __restrict__ Bt,
                                                    int* __restrict__ cnt)
{
    const int idx = blockIdx.x * NT + threadIdx.x;
    if (idx < BATCH_C) cnt[idx] = 0;
    if (idx >= 11 * 80 * BT_STRIDE) return;
    const int deg = idx / (80 * BT_STRIDE);
    const int rem = idx - deg * (80 * BT_STRIDE);
    const int col = rem / BT_STRIDE, k = rem - col * BT_STRIDE;
    const int p = col >> 4, o = col & 15;
    const int wi = (p < 4) ? 2 * p : (deg ? 2 * deg - 1 : 20);
    const float v = (k < 75 && o < 15) ? W[wi * 1125 + k * 15 + o] : 0.f;
    Bt[idx] = __builtin_bit_cast(unsigned short, (_Float16)v);
}

// ---------------------------------------------------------------------------
// prep (MFMA v4): C[128][80] = A[128][76p96] @ B[76][80] per 128-atom block.
// ---------------------------------------------------------------------------
__global__ __launch_bounds__(256) void prep_kernel(
    const float* __restrict__ x0,    // (N, 75) f32
    const unsigned short* __restrict__ Bt, // (11, 80, BT_STRIDE) fp16
    const float* __restrict__ bias,  // (21, 15)
    const int* __restrict__ mem,
    int* __restrict__ cnt,
    unsigned short* __restrict__ z,  // 4 planes of (N, 16) fp16
    unsigned short* __restrict__ srow) // (N, 16) fp16
{
    __shared__ _Float16 sx[PA * 104];           // A tile; later reused as sout

    int deg, s, c, tile;
    blk2degT<PA>(blockIdx.x, deg, s, c, tile);
    const int a0 = tile * PA;
    const int na = min(PA, c - a0);
    const int tid = threadIdx.x;
    const int wi_b = deg ? (2 * deg - 1) : 20;

    const float* src = x0 + (size_t)(s + a0) * 75;
    const int flat = na * 75;
    for (int i4 = tid; i4 * 4 < flat; i4 += NT) {
        const int i = i4 * 4;
        const f32x4 v = *reinterpret_cast<const f32x4*>(src + i);
#pragma unroll
        for (int e = 0; e < 4; ++e) {
            const int j = (i + e) / 75, f = (i + e) - j * 75;
            sx[j * 104 + f] = (_Float16)v[e];
        }
    }
    for (int i = tid; i < PA * 29; i += NT) {
        const int j = i / 29, f = 75 + (i - j * 29);
        sx[j * 104 + f] = (_Float16)0.f;
    }
    __syncthreads();

    if (tid < na) atomicAdd(&cnt[mem[s + a0 + tid]], 1);

    const int lane = tid & 63, w = tid >> 6;
    const int lrow = lane & 15;
    const int kgrp = (lane >> 4) * 8;
    const int row0 = (lane >> 4) * 4;
    const int colo = lane & 15;

    float badd = 0.f;
    if (colo < 15)
        badd = bias[wi_b * 15 + colo] + (deg ? bias[2 * (deg - 1) * 15 + colo] : 0.f);

    f16x8 af[2][3];
#pragma unroll
    for (int mt = 0; mt < 2; ++mt)
#pragma unroll
        for (int ks = 0; ks < 3; ++ks)
            af[mt][ks] = *(const f16x8*)&sx[(w * 32 + mt * 16 + lrow) * 104 + ks * 32 + kgrp];
    __syncthreads();                     // A fully consumed; sx becomes sout

    _Float16* sout = sx;                 // [PA][SO_STRIDE]
    const unsigned short* BtDeg = Bt + (size_t)deg * 80 * BT_STRIDE;

#pragma unroll
    for (int nt = 0; nt < 5; ++nt) {
        f16x8 bf[3];
#pragma unroll
        for (int ks = 0; ks < 3; ++ks)
            bf[ks] = *(const f16x8*)&BtDeg[(nt * 16 + lrow) * BT_STRIDE + ks * 32 + kgrp];
#pragma unroll
        for (int mt = 0; mt < 2; ++mt) {
            f32x4 acc = {0.f, 0.f, 0.f, 0.f};
#pragma unroll
            for (int ks = 0; ks < 3; ++ks)
                acc = __builtin_amdgcn_mfma_f32_16x16x32_f16(af[mt][ks], bf[ks], acc, 0, 0, 0);
#pragma unroll
            for (int reg = 0; reg < 4; ++reg) {
                const int ar = w * 32 + mt * 16 + row0 + reg;
                float v = acc[reg];
                if (nt == 4) v = (colo < 15) ? v + badd : 0.f;
                sout[ar * SO_STRIDE + nt * 16 + colo] = (_Float16)v;
            }
        }
    }
    __syncthreads();

    const int nunits = na * 5;
    for (int u = tid; u < nunits; u += NT) {
        const int al = u / 5, p = u - al * 5;
        const uint4* sp = reinterpret_cast<const uint4*>(&sout[al * SO_STRIDE + p * 16]);
        const uint4 v0 = sp[0], v1 = sp[1];
        const size_t atom = (size_t)(s + a0 + al);
        unsigned short* dst = (p < 4)
            ? (z + (size_t)p * ((size_t)N_ATOMS_C * 16) + atom * 16)
            : (srow + atom * 16);
        uint4* dq = reinterpret_cast<uint4*>(dst);
        dq[0] = v0; dq[1] = v1;
    }
}

// ---------------------------------------------------------------------------
// conv1: deg<=4 -> s + sum of gathered 32-B rows (2 x uint4) from z plane.
//        deg>=5 -> s + full x0-row gathers vs Wa (rare: 190K rows).
// ---------------------------------------------------------------------------
__global__ __launch_bounds__(256) void conv1_kernel(
    const float* __restrict__ x0,
    const unsigned short* __restrict__ z,     // 4 planes of (N,16)
    const unsigned short* __restrict__ srow,
    const float* __restrict__ W,
    AdjPtrs adjp,
    unsigned short* __restrict__ y1)  // (N, 16) fp16
{
    int deg, s, c, tile;
    blk2degT<NT>(blockIdx.x, deg, s, c, tile);
    const int a = tile * NT + threadIdx.x;
    if (a >= c) return;
    const int atom = s + a;

    float acc[15];
    {
        float r[16];
        load_row4<2>(reinterpret_cast<const uint4*>(srow + (size_t)atom * 16), r);
#pragma unroll
        for (int o = 0; o < 15; ++o) acc[o] = r[o];
    }

    if (deg >= 1 && deg <= 4) {
        const unsigned short* zd = z + (size_t)(deg - 1) * ((size_t)N_ATOMS_C * 16);
        const int* ad = adjp.p[deg - 1] + (size_t)a * deg;
        int nb[4];
#pragma unroll
        for (int k = 0; k < 4; ++k) nb[k] = ad[k < deg ? k : 0];
        uint4 t[4][2];
#pragma unroll
        for (int k = 0; k < 4; ++k) {
            const uint4* p = reinterpret_cast<const uint4*>(zd + (size_t)nb[k] * 16);
            t[k][0] = p[0]; t[k][1] = p[1];
        }
#pragma unroll
        for (int k = 0; k < 4; ++k) {
            if (k < deg) {
                const unsigned w[8] = {t[k][0].x, t[k][0].y, t[k][0].z, t[k][0].w,
                                       t[k][1].x, t[k][1].y, t[k][1].z, t[k][1].w};
#pragma unroll
                for (int v = 0; v < 8; ++v) {
                    const float2 lo = up2(w[v]);
                    if (2 * v < 15)     acc[2 * v]     += lo.x;
                    if (2 * v + 1 < 15) acc[2 * v + 1] += lo.y;
                }
            }
        }
    } else if (deg >= 5) {
        const float* Wa = W + 2 * (deg - 1) * 1125;
        const int* ad = adjp.p[deg - 1] + (size_t)a * deg;
#pragma unroll 1
        for (int st = 0; st < 3; ++st) {
            float r[25];
#pragma unroll
            for (int j = 0; j < 25; ++j) r[j] = 0.f;
            for (int k = 0; k < deg; ++k) {
                const float* xr = x0 + (size_t)ad[k] * 75 + st * 25;
#pragma unroll
                for (int j = 0; j < 25; ++j) r[j] += xr[j];
            }
            fma_strip<25, 15>(r, Wa + st * 25 * 15, acc);
        }
    }

    uint2* yp = reinterpret_cast<uint2*>(y1 + (size_t)atom * 16);
    float o_[16];
#pragma unroll
    for (int o = 0; o < 16; ++o) o_[o] = (o < 15) ? selu_f(acc[o]) : 0.f;
    yp[0] = make_uint2(pack2(o_[0],o_[1]),  pack2(o_[2],o_[3]));
    yp[1] = make_uint2(pack2(o_[4],o_[5]),  pack2(o_[6],o_[7]));
    yp[2] = make_uint2(pack2(o_[8],o_[9]),  pack2(o_[10],o_[11]));
    yp[3] = make_uint2(pack2(o_[12],o_[13]),pack2(o_[14],o_[15]));
}

// ---------------------------------------------------------------------------
// Generic conv (layers 2-4): thread = atom, fp16 in/out, f32 accum.
// r21: 2-deep software pipeline on the wave-uniform deg loop — row k+1's
// loads issue before row k is consumed (+NU4 uint4 ~ 16 VGPR, no clamp
// waste). Self-row load issued first; its fma covers neighbor-0 latency.
// (r20's batch-4 raised VGPR to 84 / occ 32% AND wasted ~890K clamped row
// loads for deg<4 -> 162us. r18/r19 dependent loop: 119us.)
// ---------------------------------------------------------------------------
template<int FIN, int FINP, int FO, int FOP>
__global__ __launch_bounds__(256) void conv_kernel(
    const unsigned short* __restrict__ x,  // (N, FINP) fp16
    const float* __restrict__ W,           // (21, FIN, FO)
    const float* __restrict__ bias,        // (21, FO)
    AdjPtrs adjp,
    unsigned short* __restrict__ y)        // (N, FOP) fp16
{
    static_assert(FINP % 8 == 0 && FOP % 4 == 0, "");
    constexpr int NU4 = FINP / 8;

    int deg, s, c, tile;
    blk2degT<NT>(blockIdx.x, deg, s, c, tile);
    const int a = tile * NT + threadIdx.x;
    if (a >= c) return;
    const int atom = s + a;

    const int wi_a = (deg == 0) ? 20 : 2 * (deg - 1);
    const int wi_b = (deg == 0) ? 20 : 2 * deg - 1;
    const float* Wa = W + wi_a * FIN * FO;
    const float* Wb = W + wi_b * FIN * FO;

    float acc[FO];
#pragma unroll
    for (int o = 0; o < FO; ++o)
        acc[o] = bias[wi_b * FO + o] + ((deg > 0) ? bias[wi_a * FO + o] : 0.f);

    if (deg > 0) {
        const int* myadj = adjp.p[deg - 1] + (size_t)a * deg;
        // issue first-neighbor load, then self load; self fma covers latency
        uint4 cur[NU4];
        {
            const uint4* p = reinterpret_cast<const uint4*>(x + (size_t)myadj[0] * FINP);
#pragma unroll
            for (int v = 0; v < NU4; ++v) cur[v] = p[v];
        }
        {
            float r[FINP];
            load_row4<NU4>(reinterpret_cast<const uint4*>(x + (size_t)atom * FINP), r);
            fma_strip<FIN, FO>(r, Wb, acc);
        }
        float rel[FINP];
#pragma unroll
        for (int f = 0; f < FINP; ++f) rel[f] = 0.f;
#pragma unroll 1
        for (int k = 1; k < deg; ++k) {        // wave-uniform bound
            uint4 nxt[NU4];
            const uint4* p = reinterpret_cast<const uint4*>(x + (size_t)myadj[k] * FINP);
#pragma unroll
            for (int v = 0; v < NU4; ++v) nxt[v] = p[v];   // issue next...
            acc_u4<NU4>(cur, rel);                          // ...consume current
#pragma unroll
            for (int v = 0; v < NU4; ++v) cur[v] = nxt[v];
        }
        acc_u4<NU4>(cur, rel);
        fma_strip<FIN, FO>(rel, Wa, acc);
    } else {
        float r[FINP];
        load_row4<NU4>(reinterpret_cast<const uint4*>(x + (size_t)atom * FINP), r);
        fma_strip<FIN, FO>(r, Wb, acc);
    }

    float outv[FOP];
#pragma unroll
    for (int o = 0; o < FOP; ++o) outv[o] = (o < FO) ? selu_f(acc[o]) : 0.f;
    uint2* yp = reinterpret_cast<uint2*>(y + (size_t)atom * FOP);
#pragma unroll
    for (int v = 0; v < FOP / 4; ++v)
        yp[v] = make_uint2(pack2(outv[4*v], outv[4*v+1]),
                           pack2(outv[4*v+2], outv[4*v+3]));
}

// ---------------------------------------------------------------------------
// inverted-index build: (zero fused in bprep) -> count in prep -> scan -> scatter
// ---------------------------------------------------------------------------
__global__ __launch_bounds__(1024) void scan_kernel(const int* __restrict__ cnt,
                                                    int* __restrict__ base,
                                                    int* __restrict__ cursor) {
    __shared__ int part[1024];
    const int tid = threadIdx.x;
    constexpr int CH = 24;
    const int i0 = tid * CH;
    int sum = 0;
    for (int j = 0; j < CH; ++j) { const int i = i0 + j; if (i < BATCH_C) sum += cnt[i]; }
    part[tid] = sum;
    __syncthreads();
    for (int off = 1; off < 1024; off <<= 1) {
        const int v = (tid >= off) ? part[tid - off] : 0;
        __syncthreads(); part[tid] += v; __syncthreads();
    }
    int run = part[tid] - sum;
    for (int j = 0; j < CH; ++j) {
        const int i = i0 + j;
        if (i < BATCH_C) { base[i] = run; cursor[i] = run; run += cnt[i]; }
    }
    if (tid == 1023) base[BATCH_C] = part[1023];
}
__global__ __launch_bounds__(256) void scatter_kernel(const int* __restrict__ mem,
                                                      int* __restrict__ cursor,
                                                      int* __restrict__ alist) {
    const int i = blockIdx.x * NT + threadIdx.x;
    if (i < N_ATOMS_C) { const int p = atomicAdd(&cursor[mem[i]], 1); alist[p] = i; }
}

// ---------------------------------------------------------------------------
// one wave per molecule: register sum/max over fp16 y4 rows, fused
// tanh -> 72x24 dense -> pairwise softmax
// ---------------------------------------------------------------------------
__global__ __launch_bounds__(256) void reduce_dense_kernel(
    const unsigned short* __restrict__ y4,  // (N, 36) fp16
    const int* __restrict__ base, const int* __restrict__ alist,
    const float* __restrict__ Wd, const float* __restrict__ bd,
    float* __restrict__ out)
{
    __shared__ float sW[72 * 24];
    __shared__ float sb[24];
    __shared__ float molf[4][72];

    const int tid = threadIdx.x;
    for (int i = tid; i < 72 * 24; i += NT) sW[i] = Wd[i];
    if (tid < 24) sb[tid] = bd[tid];
    __syncthreads();

    const int w = tid >> 6, lane = tid & 63;
    const int mol = blockIdx.x * 4 + w;
    const int b0 = base[mol], b1 = base[mol + 1];

    if (lane < 36) {
        float s = 0.f, mx = -INFINITY;
        for (int k = b0; k < b1; ++k) {
            const int atom = alist[k];
            const float v = __half2float(__builtin_bit_cast(__half,
                                y4[(size_t)atom * 36 + lane]));
            s += v; mx = fmaxf(mx, v);
        }
        molf[w][lane] = tanhf(s);
        molf[w][36 + lane] = tanhf(mx);
    }
    __syncthreads();

    if (lane < 24) {
        float l = sb[lane];
#pragma unroll
        for (int f = 0; f < 72; ++f) l += molf[w][f] * sW[f * 24 + lane];
        const float lp = __shfl_xor(l, 1);
        const float m2 = fmaxf(l, lp);
        const float e = expf(l - m2), ep = expf(lp - m2);
        out[(size_t)mol * 24 + lane] = e / (e + ep);
    }
}

// ---------------------------------------------------------------------------
extern "C" void kernel_launch(void* const* d_in, const int* in_sizes, int n_in,
                              void* d_out, int out_size, void* d_ws, size_t ws_size,
                              hipStream_t stream)
{
    const float* x0         = (const float*)d_in[0];
    const int*   membership = (const int*)d_in[2];
    AdjPtrs adj;
    for (int d = 0; d < 10; ++d) adj.p[d] = (const int*)d_in[3 + d];
    const float *W1=(const float*)d_in[13], *b1=(const float*)d_in[14];
    const float *W2=(const float*)d_in[15], *b2=(const float*)d_in[16];
    const float *W3=(const float*)d_in[17], *b3=(const float*)d_in[18];
    const float *W4=(const float*)d_in[19], *b4=(const float*)d_in[20];
    const float *Wd=(const float*)d_in[21], *bd=(const float*)d_in[22];

    // ws layout (bytes):
    //  A [0 .. 81.6M): z planes 4 x (N,16) fp16 = 76.8M (dead after conv1);
    //                  then y2 = A[0..38.4M) (stride 32), y4 = A[38.4..81.6M)
    //  B [szA .. +38.4M): srow (19.2M) + y1 (19.2M at +19.2M);
    //                  after L2 both dead -> y3 = B[0..38.4M)
    //  ints after B; Bt (fp16 B tiles, 183KB) after ints
    const size_t szA = 81600000;
    const size_t szB = 38400000;
    const size_t nInts = (size_t)N_ATOMS_C + (BATCH_C + 1) + BATCH_C + BATCH_C;
    const size_t btOff = szA + szB + nInts * 4;
    if (ws_size < btOff + (size_t)11 * 80 * BT_STRIDE * 2) return;

    char* base0 = (char*)d_ws;
    unsigned short* zbuf = (unsigned short*)base0;
    unsigned short* y2   = (unsigned short*)base0;                      // alias A
    unsigned short* y4   = (unsigned short*)(base0 + 38400000);         // alias A tail
    unsigned short* srow = (unsigned short*)(base0 + szA);
    unsigned short* y1   = (unsigned short*)(base0 + szA + 19200000);
    unsigned short* y3   = (unsigned short*)(base0 + szA);              // alias B after L2
    int* alist  = (int*)(base0 + szA + szB);
    int* base   = alist + N_ATOMS_C;
    int* cursor = base + (BATCH_C + 1);
    int* cnt    = cursor + BATCH_C;
    unsigned short* Bt = (unsigned short*)(base0 + btOff);

    int nblk = 0, nblkp = 0;
    for (int d = 0; d < 11; ++d) {
        nblk  += (K_COUNTS[d] + NT - 1) / NT;
        nblkp += (K_COUNTS[d] + PA - 1) / PA;
    }
    const int nb_atoms = (N_ATOMS_C + NT - 1) / NT;

    bprep_kernel<<<(11 * 80 * BT_STRIDE + NT - 1) / NT, NT, 0, stream>>>(W1, Bt, cnt);
    prep_kernel<<<nblkp, NT, 0, stream>>>(x0, Bt, b1, membership, cnt, zbuf, srow);
    scan_kernel<<<1, 1024, 0, stream>>>(cnt, base, cursor);
    scatter_kernel<<<nb_atoms, NT, 0, stream>>>(membership, cursor, alist);

    conv1_kernel<<<nblk, NT, 0, stream>>>(x0, zbuf, srow, W1, adj, y1);
    conv_kernel<15,16,20,32><<<nblk, NT, 0, stream>>>(y1, W2, b2, adj, y2);
    conv_kernel<20,32,27,32><<<nblk, NT, 0, stream>>>(y2, W3, b3, adj, y3);
    conv_kernel<27,32,36,36><<<nblk, NT, 0, stream>>>(y3, W4, b4, adj, y4);

    reduce_dense_kernel<<<BATCH_C / 4, NT, 0, stream>>>(y4, base, alist, Wd, bd, (float*)d_out);
}

// Round 22
// 519.160 us; speedup vs baseline: 1.3160x; 1.3160x over previous
//
#include <hip/hip_runtime.h>
#include <hip/hip_fp16.h>
#include <cstdint>

#define NT 256
#define PA 128                 // prep atoms per block (4 waves x 2 M-tiles)
#define N_ATOMS_C 600000
#define BATCH_C 24000
#define BT_STRIDE 104          // Bt k-stride (halves)
#define SO_STRIDE 88           // sout row stride (halves, 16B-aligned rows)

constexpr int K_COUNTS[11] = {10000,130000,170000,160000,100000,15000,5000,2500,2500,2500,2500};
constexpr int K_STARTS[11] = {0,10000,140000,310000,470000,570000,585000,590000,592500,595000,597500};
// heavy-degree-first dispatch order
constexpr int DORD[11] = {10,9,8,7,6,5,4,3,2,1,0};

struct AdjPtrs { const int* p[10]; };

typedef _Float16 f16x8 __attribute__((ext_vector_type(8)));
typedef float f32x4 __attribute__((ext_vector_type(4)));

__device__ __forceinline__ float selu_f(float x) {
    const float scale = 1.0507009873554805f;
    const float alpha = 1.6732632423543772f;
    return scale * (x > 0.f ? x : alpha * expm1f(x));
}

__device__ __forceinline__ float2 up2(unsigned u) {
    const __half2 h = __builtin_bit_cast(__half2, u);
    return __half22float2(h);
}
__device__ __forceinline__ unsigned pack2(float a, float b) {
    const __half2 h = __float22half2_rn(make_float2(a, b));
    return __builtin_bit_cast(unsigned, h);
}

template<int NLD4>
__device__ __forceinline__ void load_row(const uint2* __restrict__ p, float* r) {
#pragma unroll
    for (int v = 0; v < NLD4; ++v) {
        const uint2 t = p[v];
        const float2 a = up2(t.x), b = up2(t.y);
        r[4*v] = a.x; r[4*v+1] = a.y; r[4*v+2] = b.x; r[4*v+3] = b.y;
    }
}
template<int NLD4>
__device__ __forceinline__ void add_row(const uint2* __restrict__ p, float* r) {
#pragma unroll
    for (int v = 0; v < NLD4; ++v) {
        const uint2 t = p[v];
        const float2 a = up2(t.x), b = up2(t.y);
        r[4*v] += a.x; r[4*v+1] += a.y; r[4*v+2] += b.x; r[4*v+3] += b.y;
    }
}
template<int NF, int FO>
__device__ __forceinline__ void fma_strip(const float* r, const float* __restrict__ w,
                                          float* acc) {
#pragma unroll
    for (int f = 0; f < NF; ++f)
#pragma unroll
        for (int o = 0; o < FO; ++o)
            acc[o] = fmaf(r[f], w[f * FO + o], acc[o]);
}

// block -> (degree, segment start, count, tile index within segment)
template<int TB>
__device__ __forceinline__ void blk2degT(int blk, int& deg, int& s, int& cnt, int& tile) {
    deg = 0; s = 0; cnt = 0; tile = 0;
#pragma unroll
    for (int di = 0; di < 11; ++di) {
        const int d = DORD[di];
        const int nb = (K_COUNTS[d] + TB - 1) / TB;
        if (blk < nb) { deg = d; s = K_STARTS[d]; cnt = K_COUNTS[d]; tile = blk; return; }
        blk -= nb;
    }
}

// ---------------------------------------------------------------------------
// bprep: build fp16 B^T tiles ONCE: Bt[deg][col][k], col=16p+o (p=proj, o=out),
// k = input feat (0 pad past 75 / o=15).
// ---------------------------------------------------------------------------
__global__ __launch_bounds__(256) void bprep_kernel(const float* __restrict__ W,
                                                    unsigned short* __restrict__ Bt)
{
    const int idx = blockIdx.x * NT + threadIdx.x;
    if (idx >= 11 * 80 * BT_STRIDE) return;
    const int deg = idx / (80 * BT_STRIDE);
    const int rem = idx - deg * (80 * BT_STRIDE);
    const int col = rem / BT_STRIDE, k = rem - col * BT_STRIDE;
    const int p = col >> 4, o = col & 15;
    const int wi = (p < 4) ? 2 * p : (deg ? 2 * deg - 1 : 20);
    const float v = (k < 75 && o < 15) ? W[wi * 1125 + k * 15 + o] : 0.f;
    Bt[idx] = __builtin_bit_cast(unsigned short, (_Float16)v);
}

// ---------------------------------------------------------------------------
// prep (MFMA v4): C[128][80] = A[128][76p96] @ B[76][80] per 128-atom block.
// B fragments per-lane direct from precomputed fp16 Bt (L1-hot). LDS = A-only
// 26.6KB -> 6 blocks/CU. Epilogue via LDS transpose -> 2 x uint4 32B stores.
// ---------------------------------------------------------------------------
__global__ __launch_bounds__(256) void prep_kernel(
    const float* __restrict__ x0,    // (N, 75) f32
    const unsigned short* __restrict__ Bt, // (11, 80, BT_STRIDE) fp16
    const float* __restrict__ bias,  // (21, 15)
    const int* __restrict__ mem,
    int* __restrict__ cnt,
    unsigned short* __restrict__ z,  // 4 planes of (N, 16) fp16
    unsigned short* __restrict__ srow) // (N, 16) fp16
{
    __shared__ _Float16 sx[PA * 104];           // A tile; later reused as sout

    int deg, s, c, tile;
    blk2degT<PA>(blockIdx.x, deg, s, c, tile);
    const int a0 = tile * PA;
    const int na = min(PA, c - a0);
    const int tid = threadIdx.x;
    const int wi_b = deg ? (2 * deg - 1) : 20;

    // stage A: na x 75 f32 -> fp16 LDS via float4
    const float* src = x0 + (size_t)(s + a0) * 75;
    const int flat = na * 75;
    for (int i4 = tid; i4 * 4 < flat; i4 += NT) {
        const int i = i4 * 4;
        const f32x4 v = *reinterpret_cast<const f32x4*>(src + i);
#pragma unroll
        for (int e = 0; e < 4; ++e) {
            const int j = (i + e) / 75, f = (i + e) - j * 75;
            sx[j * 104 + f] = (_Float16)v[e];
        }
    }
    // zero A pad cols 75..103
    for (int i = tid; i < PA * 29; i += NT) {
        const int j = i / 29, f = 75 + (i - j * 29);
        sx[j * 104 + f] = (_Float16)0.f;
    }
    __syncthreads();

    if (tid < na) atomicAdd(&cnt[mem[s + a0 + tid]], 1);

    const int lane = tid & 63, w = tid >> 6;
    const int lrow = lane & 15;          // A row in tile / B col
    const int kgrp = (lane >> 4) * 8;    // k offset within K-step
    const int row0 = (lane >> 4) * 4;    // C row base
    const int colo = lane & 15;          // C col

    float badd = 0.f;
    if (colo < 15)
        badd = bias[wi_b * 15 + colo] + (deg ? bias[2 * (deg - 1) * 15 + colo] : 0.f);

    // hoist A fragments (2 M-tiles x 3 K-steps per wave), then repurpose sx
    f16x8 af[2][3];
#pragma unroll
    for (int mt = 0; mt < 2; ++mt)
#pragma unroll
        for (int ks = 0; ks < 3; ++ks)
            af[mt][ks] = *(const f16x8*)&sx[(w * 32 + mt * 16 + lrow) * 104 + ks * 32 + kgrp];
    __syncthreads();                     // A fully consumed; sx becomes sout

    _Float16* sout = sx;                 // [PA][SO_STRIDE]
    const unsigned short* BtDeg = Bt + (size_t)deg * 80 * BT_STRIDE;

#pragma unroll
    for (int nt = 0; nt < 5; ++nt) {     // N-tile == projection p
        f16x8 bf[3];
#pragma unroll
        for (int ks = 0; ks < 3; ++ks)
            bf[ks] = *(const f16x8*)&BtDeg[(nt * 16 + lrow) * BT_STRIDE + ks * 32 + kgrp];
#pragma unroll
        for (int mt = 0; mt < 2; ++mt) {
            f32x4 acc = {0.f, 0.f, 0.f, 0.f};
#pragma unroll
            for (int ks = 0; ks < 3; ++ks)
                acc = __builtin_amdgcn_mfma_f32_16x16x32_f16(af[mt][ks], bf[ks], acc, 0, 0, 0);
#pragma unroll
            for (int reg = 0; reg < 4; ++reg) {
                const int ar = w * 32 + mt * 16 + row0 + reg;
                float v = acc[reg];
                if (nt == 4) v = (colo < 15) ? v + badd : 0.f;
                sout[ar * SO_STRIDE + nt * 16 + colo] = (_Float16)v;
            }
        }
    }
    __syncthreads();

    // vectorized write-out: unit = (atom_l, plane); 32B contiguous per unit
    const int nunits = na * 5;
    for (int u = tid; u < nunits; u += NT) {
        const int al = u / 5, p = u - al * 5;
        const uint4* sp = reinterpret_cast<const uint4*>(&sout[al * SO_STRIDE + p * 16]);
        const uint4 v0 = sp[0], v1 = sp[1];
        const size_t atom = (size_t)(s + a0 + al);
        unsigned short* dst = (p < 4)
            ? (z + (size_t)p * ((size_t)N_ATOMS_C * 16) + atom * 16)
            : (srow + atom * 16);
        uint4* dq = reinterpret_cast<uint4*>(dst);
        dq[0] = v0; dq[1] = v1;
    }
}

// ---------------------------------------------------------------------------
// conv1: deg<=4 -> s + sum of gathered 32-B rows (2 x uint4) from z plane.
//        deg>=5 -> s + full x0-row gathers vs Wa (rare: 190K rows).
// ---------------------------------------------------------------------------
__global__ __launch_bounds__(256) void conv1_kernel(
    const float* __restrict__ x0,
    const unsigned short* __restrict__ z,     // 4 planes of (N,16)
    const unsigned short* __restrict__ srow,
    const float* __restrict__ W,
    AdjPtrs adjp,
    unsigned short* __restrict__ y1)  // (N, 16) fp16
{
    int deg, s, c, tile;
    blk2degT<NT>(blockIdx.x, deg, s, c, tile);
    const int a = tile * NT + threadIdx.x;
    if (a >= c) return;
    const int atom = s + a;

    float acc[15];
    {
        const uint2* sp = reinterpret_cast<const uint2*>(srow + (size_t)atom * 16);
        float r[16];
        load_row<4>(sp, r);
#pragma unroll
        for (int o = 0; o < 15; ++o) acc[o] = r[o];
    }

    if (deg >= 1 && deg <= 4) {
        const unsigned short* zd = z + (size_t)(deg - 1) * ((size_t)N_ATOMS_C * 16);
        const int* ad = adjp.p[deg - 1] + (size_t)a * deg;
        int nb[4];
#pragma unroll
        for (int k = 0; k < 4; ++k) nb[k] = ad[k < deg ? k : 0];
        uint4 t[4][2];
#pragma unroll
        for (int k = 0; k < 4; ++k) {
            const uint4* p = reinterpret_cast<const uint4*>(zd + (size_t)nb[k] * 16);
            t[k][0] = p[0]; t[k][1] = p[1];
        }
#pragma unroll
        for (int k = 0; k < 4; ++k) {
            if (k < deg) {
                const unsigned w[8] = {t[k][0].x, t[k][0].y, t[k][0].z, t[k][0].w,
                                       t[k][1].x, t[k][1].y, t[k][1].z, t[k][1].w};
#pragma unroll
                for (int v = 0; v < 8; ++v) {
                    const float2 lo = up2(w[v]);
                    if (2 * v < 15)     acc[2 * v]     += lo.x;
                    if (2 * v + 1 < 15) acc[2 * v + 1] += lo.y;
                }
            }
        }
    } else if (deg >= 5) {
        const float* Wa = W + 2 * (deg - 1) * 1125;
        const int* ad = adjp.p[deg - 1] + (size_t)a * deg;
#pragma unroll 1
        for (int st = 0; st < 3; ++st) {
            float r[25];
#pragma unroll
            for (int j = 0; j < 25; ++j) r[j] = 0.f;
            for (int k = 0; k < deg; ++k) {
                const float* xr = x0 + (size_t)ad[k] * 75 + st * 25;
#pragma unroll
                for (int j = 0; j < 25; ++j) r[j] += xr[j];
            }
            fma_strip<25, 15>(r, Wa + st * 25 * 15, acc);
        }
    }

    uint2* yp = reinterpret_cast<uint2*>(y1 + (size_t)atom * 16);
    float o_[16];
#pragma unroll
    for (int o = 0; o < 16; ++o) o_[o] = (o < 15) ? selu_f(acc[o]) : 0.f;
    yp[0] = make_uint2(pack2(o_[0],o_[1]),  pack2(o_[2],o_[3]));
    yp[1] = make_uint2(pack2(o_[4],o_[5]),  pack2(o_[6],o_[7]));
    yp[2] = make_uint2(pack2(o_[8],o_[9]),  pack2(o_[10],o_[11]));
    yp[3] = make_uint2(pack2(o_[12],o_[13]),pack2(o_[14],o_[15]));
}

// ---------------------------------------------------------------------------
// Generic conv (layers 2-4): thread = atom, fp16 in/out, f32 accum.
// (r18 proven-best structure: FS strips + uint2 loads, 56 VGPR / occ 38%.
//  r19 uint4 = same 119us; r20 batch-4 = 162us; r21 pipeline = 178us —
//  the 119us plateau is the random 64B-line fill ceiling, not issue shape.)
// ---------------------------------------------------------------------------
template<int FIN, int FINP, int FO, int FOP, int FS>
__global__ __launch_bounds__(256) void conv_kernel(
    const unsigned short* __restrict__ x,  // (N, FINP) fp16
    const float* __restrict__ W,           // (21, FIN, FO)
    const float* __restrict__ bias,        // (21, FO)
    AdjPtrs adjp,
    unsigned short* __restrict__ y)        // (N, FOP) fp16
{
    static_assert(FS % 4 == 0 && FINP % 4 == 0 && FOP % 4 == 0, "");
    constexpr int NSF = FIN / FS;
    constexpr int TF  = FIN - NSF * FS;
    constexpr int TLD4 = (TF + 3) / 4;
    static_assert(NSF * FS + TLD4 * 4 <= FINP, "tail reads past row");

    int deg, s, c, tile;
    blk2degT<NT>(blockIdx.x, deg, s, c, tile);
    const int a = tile * NT + threadIdx.x;
    if (a >= c) return;
    const int atom = s + a;

    const int wi_a = (deg == 0) ? 20 : 2 * (deg - 1);
    const int wi_b = (deg == 0) ? 20 : 2 * deg - 1;
    const float* Wa = W + wi_a * FIN * FO;
    const float* Wb = W + wi_b * FIN * FO;

    float acc[FO];
#pragma unroll
    for (int o = 0; o < FO; ++o)
        acc[o] = bias[wi_b * FO + o] + ((deg > 0) ? bias[wi_a * FO + o] : 0.f);

    const int* myadj = (deg > 0) ? (adjp.p[deg - 1] + (size_t)a * deg) : nullptr;
    const uint2* selfrow = reinterpret_cast<const uint2*>(x + (size_t)atom * FINP);

#pragma unroll 1
    for (int st = 0; st < NSF; ++st) {
        const int f0 = st * FS;
        float r[FS];
        load_row<FS / 4>(selfrow + (f0 >> 2), r);
        fma_strip<FS, FO>(r, Wb + f0 * FO, acc);
        if (deg > 0) {
#pragma unroll
            for (int f = 0; f < FS; ++f) r[f] = 0.f;
            for (int k = 0; k < deg; ++k)
                add_row<FS / 4>(reinterpret_cast<const uint2*>(
                    x + (size_t)myadj[k] * FINP) + (f0 >> 2), r);
            fma_strip<FS, FO>(r, Wa + f0 * FO, acc);
        }
    }
    if constexpr (TF > 0) {
        constexpr int f0 = NSF * FS;
        float r[TLD4 * 4];
        load_row<TLD4>(selfrow + (f0 >> 2), r);
        fma_strip<TF, FO>(r, Wb + f0 * FO, acc);
        if (deg > 0) {
#pragma unroll
            for (int f = 0; f < TLD4 * 4; ++f) r[f] = 0.f;
            for (int k = 0; k < deg; ++k)
                add_row<TLD4>(reinterpret_cast<const uint2*>(
                    x + (size_t)myadj[k] * FINP) + (f0 >> 2), r);
            fma_strip<TF, FO>(r, Wa + f0 * FO, acc);
        }
    }

    float outv[FOP];
#pragma unroll
    for (int o = 0; o < FOP; ++o) outv[o] = (o < FO) ? selu_f(acc[o]) : 0.f;
    uint2* yp = reinterpret_cast<uint2*>(y + (size_t)atom * FOP);
#pragma unroll
    for (int v = 0; v < FOP / 4; ++v)
        yp[v] = make_uint2(pack2(outv[4*v], outv[4*v+1]),
                           pack2(outv[4*v+2], outv[4*v+3]));
}

// ---------------------------------------------------------------------------
// inverted-index build: zero -> (count fused in prep) -> scan -> scatter
// ---------------------------------------------------------------------------
__global__ __launch_bounds__(256) void zero_cnt_kernel(int* __restrict__ cnt) {
    const int i = blockIdx.x * NT + threadIdx.x;
    if (i < BATCH_C) cnt[i] = 0;
}
__global__ __launch_bounds__(1024) void scan_kernel(const int* __restrict__ cnt,
                                                    int* __restrict__ base,
                                                    int* __restrict__ cursor) {
    __shared__ int part[1024];
    const int tid = threadIdx.x;
    constexpr int CH = 24;
    const int i0 = tid * CH;
    int sum = 0;
    for (int j = 0; j < CH; ++j) { const int i = i0 + j; if (i < BATCH_C) sum += cnt[i]; }
    part[tid] = sum;
    __syncthreads();
    for (int off = 1; off < 1024; off <<= 1) {
        const int v = (tid >= off) ? part[tid - off] : 0;
        __syncthreads(); part[tid] += v; __syncthreads();
    }
    int run = part[tid] - sum;
    for (int j = 0; j < CH; ++j) {
        const int i = i0 + j;
        if (i < BATCH_C) { base[i] = run; cursor[i] = run; run += cnt[i]; }
    }
    if (tid == 1023) base[BATCH_C] = part[1023];
}
__global__ __launch_bounds__(256) void scatter_kernel(const int* __restrict__ mem,
                                                      int* __restrict__ cursor,
                                                      int* __restrict__ alist) {
    const int i = blockIdx.x * NT + threadIdx.x;
    if (i < N_ATOMS_C) { const int p = atomicAdd(&cursor[mem[i]], 1); alist[p] = i; }
}

// ---------------------------------------------------------------------------
// one wave per molecule: register sum/max over fp16 y4 rows, fused
// tanh -> 72x24 dense -> pairwise softmax
// ---------------------------------------------------------------------------
__global__ __launch_bounds__(256) void reduce_dense_kernel(
    const unsigned short* __restrict__ y4,  // (N, 36) fp16
    const int* __restrict__ base, const int* __restrict__ alist,
    const float* __restrict__ Wd, const float* __restrict__ bd,
    float* __restrict__ out)
{
    __shared__ float sW[72 * 24];
    __shared__ float sb[24];
    __shared__ float molf[4][72];

    const int tid = threadIdx.x;
    for (int i = tid; i < 72 * 24; i += NT) sW[i] = Wd[i];
    if (tid < 24) sb[tid] = bd[tid];
    __syncthreads();

    const int w = tid >> 6, lane = tid & 63;
    const int mol = blockIdx.x * 4 + w;
    const int b0 = base[mol], b1 = base[mol + 1];

    if (lane < 36) {
        float s = 0.f, mx = -INFINITY;
        for (int k = b0; k < b1; ++k) {
            const int atom = alist[k];
            const float v = __half2float(__builtin_bit_cast(__half,
                                y4[(size_t)atom * 36 + lane]));
            s += v; mx = fmaxf(mx, v);
        }
        molf[w][lane] = tanhf(s);
        molf[w][36 + lane] = tanhf(mx);
    }
    __syncthreads();

    if (lane < 24) {
        float l = sb[lane];
#pragma unroll
        for (int f = 0; f < 72; ++f) l += molf[w][f] * sW[f * 24 + lane];
        const float lp = __shfl_xor(l, 1);
        const float m2 = fmaxf(l, lp);
        const float e = expf(l - m2), ep = expf(lp - m2);
        out[(size_t)mol * 24 + lane] = e / (e + ep);
    }
}

// ---------------------------------------------------------------------------
extern "C" void kernel_launch(void* const* d_in, const int* in_sizes, int n_in,
                              void* d_out, int out_size, void* d_ws, size_t ws_size,
                              hipStream_t stream)
{
    const float* x0         = (const float*)d_in[0];
    const int*   membership = (const int*)d_in[2];
    AdjPtrs adj;
    for (int d = 0; d < 10; ++d) adj.p[d] = (const int*)d_in[3 + d];
    const float *W1=(const float*)d_in[13], *b1=(const float*)d_in[14];
    const float *W2=(const float*)d_in[15], *b2=(const float*)d_in[16];
    const float *W3=(const float*)d_in[17], *b3=(const float*)d_in[18];
    const float *W4=(const float*)d_in[19], *b4=(const float*)d_in[20];
    const float *Wd=(const float*)d_in[21], *bd=(const float*)d_in[22];

    // ws layout (bytes):
    //  A [0 .. 81.6M): z planes 4 x (N,16) fp16 = 76.8M (dead after conv1);
    //                  then y2 = A[0..38.4M) (stride 32), y4 = A[38.4..81.6M)
    //  B [szA .. +38.4M): srow (19.2M) + y1 (19.2M at +19.2M);
    //                  after L2 both dead -> y3 = B[0..38.4M)
    //  ints after B; Bt (fp16 B tiles, 183KB) after ints
    const size_t szA = 81600000;
    const size_t szB = 38400000;
    const size_t nInts = (size_t)N_ATOMS_C + (BATCH_C + 1) + BATCH_C + BATCH_C;
    const size_t btOff = szA + szB + nInts * 4;
    if (ws_size < btOff + (size_t)11 * 80 * BT_STRIDE * 2) return;

    char* base0 = (char*)d_ws;
    unsigned short* zbuf = (unsigned short*)base0;
    unsigned short* y2   = (unsigned short*)base0;                      // alias A
    unsigned short* y4   = (unsigned short*)(base0 + 38400000);         // alias A tail
    unsigned short* srow = (unsigned short*)(base0 + szA);
    unsigned short* y1   = (unsigned short*)(base0 + szA + 19200000);
    unsigned short* y3   = (unsigned short*)(base0 + szA);              // alias B after L2
    int* alist  = (int*)(base0 + szA + szB);
    int* base   = alist + N_ATOMS_C;
    int* cursor = base + (BATCH_C + 1);
    int* cnt    = cursor + BATCH_C;
    unsigned short* Bt = (unsigned short*)(base0 + btOff);

    int nblk = 0, nblkp = 0;
    for (int d = 0; d < 11; ++d) {
        nblk  += (K_COUNTS[d] + NT - 1) / NT;
        nblkp += (K_COUNTS[d] + PA - 1) / PA;
    }
    const int nb_atoms = (N_ATOMS_C + NT - 1) / NT;

    zero_cnt_kernel<<<(BATCH_C + NT - 1) / NT, NT, 0, stream>>>(cnt);
    bprep_kernel<<<(11 * 80 * BT_STRIDE + NT - 1) / NT, NT, 0, stream>>>(W1, Bt);
    prep_kernel<<<nblkp, NT, 0, stream>>>(x0, Bt, b1, membership, cnt, zbuf, srow);
    scan_kernel<<<1, 1024, 0, stream>>>(cnt, base, cursor);
    scatter_kernel<<<nb_atoms, NT, 0, stream>>>(membership, cursor, alist);

    conv1_kernel<<<nblk, NT, 0, stream>>>(x0, zbuf, srow, W1, adj, y1);
    conv_kernel<15,16,20,32,16><<<nblk, NT, 0, stream>>>(y1, W2, b2, adj, y2);
    conv_kernel<20,32,27,32,32><<<nblk, NT, 0, stream>>>(y2, W3, b3, adj, y3);
    conv_kernel<27,32,36,36,32><<<nblk, NT, 0, stream>>>(y3, W4, b4, adj, y4);

    reduce_dense_kernel<<<BATCH_C / 4, NT, 0, stream>>>(y4, base, alist, Wd, bd, (float*)d_out);
}